// Round 6
// baseline (1015.475 us; speedup 1.0000x reference)
//
#include <hip/hip_runtime.h>
#include <hip/hip_bf16.h>
#include <cstddef>

// Problem constants (match reference)
constexpr int NN = 50000;   // nodes
constexpr int EE = 600000;  // edges
constexpr int BBg = 256;    // graphs

typedef __attribute__((ext_vector_type(8))) short short8;
typedef __attribute__((ext_vector_type(4))) float f32x4;

// bf16 round-to-nearest-even split helpers
__device__ __forceinline__ unsigned short bf16_rne(float f) {
    unsigned int u = __float_as_uint(f);
    unsigned int r = u + 0x7fffu + ((u >> 16) & 1u);
    return (unsigned short)(r >> 16);
}
__device__ __forceinline__ float bf16_tof(unsigned short h) {
    return __uint_as_float(((unsigned int)h) << 16);
}

// ---------------------------------------------------------------------------
// Split conv weights into pre-swizzled per-cblock LDS images.
// Image: [l][cb][64 cols][384 k'] bf16, elem ^= ((c&7)<<3).
// ---------------------------------------------------------------------------
__global__ __launch_bounds__(256) void bake_bimg(
    const float* __restrict__ Wr1, const float* __restrict__ Wl1,
    const float* __restrict__ Wr2, const float* __restrict__ Wl2,
    const float* __restrict__ Wr3, const float* __restrict__ Wl3,
    unsigned short* __restrict__ bimg)
{
    int t = blockIdx.x * 256 + threadIdx.x;      // 3*4*64*384 = 294912
    const int kp = t % 384;
    int rest = t / 384;
    const int c = rest & 63;  rest >>= 6;
    const int cb = rest & 3;  rest >>= 2;
    const int l = rest;                           // 0..2
    const int kk = kp & 127;
    const int gc = cb * 64 + c;
    const float* W;
    if (gc < 128) W = (l == 0) ? Wr1 : (l == 1) ? Wr2 : Wr3;
    else          W = (l == 0) ? Wl1 : (l == 1) ? Wl2 : Wl3;
    const float v = W[kk * 128 + (gc & 127)];
    const unsigned short hi = bf16_rne(v);
    unsigned short out = hi;
    if (kp >= 256) out = bf16_rne(v - bf16_tof(hi));
    const int e = (c * 384 + kp) ^ ((c & 7) << 3);
    bimg[(l * 4 + cb) * 24576 + e] = out;
}

// x (f32 [N][128]) -> x2 (bf16 [N][256] = [ah|al])
__global__ __launch_bounds__(256) void prep_x2(const float* __restrict__ x,
                                               unsigned short* __restrict__ x2)
{
    const int t = blockIdx.x * 256 + threadIdx.x;
    if (t >= NN * 128) return;
    const int n = t >> 7, k = t & 127;
    const float v = x[t];
    const unsigned short hi = bf16_rne(v);
    x2[(size_t)n * 256 + k] = hi;
    x2[(size_t)n * 256 + 128 + k] = bf16_rne(v - bf16_tof(hi));
}

// ---------------------------------------------------------------------------
// Combined LSTM weight wt[k][j] = W_ih[j][k] (+W_hh[j][k] for k<384), split
// hi/lo bf16, fragment-layout image: wt2[v][k'/8][1536 cols][8].
// ---------------------------------------------------------------------------
__global__ __launch_bounds__(256) void bake_wt2(const float* __restrict__ w_ih,
                                                const float* __restrict__ w_hh,
                                                unsigned short* __restrict__ wt2)
{
    const int t = blockIdx.x * 256 + threadIdx.x;  // 2*96*1536*8 = 2,359,296
    const int o = t & 7;
    const int j = (t >> 3) % 1536;
    const int rest = (t >> 3) / 1536;  // 0..191
    const int kg = rest % 96;
    const int v = rest / 96;           // 0=hi, 1=lo
    const int k = kg * 8 + o;          // 0..767
    float val = w_ih[(size_t)j * 768 + k];
    if (k < 384) val += w_hh[(size_t)j * 384 + k];
    const unsigned short hi = bf16_rne(val);
    wt2[t] = v ? bf16_rne(val - bf16_tof(hi)) : hi;
}

// ---------------------------------------------------------------------------
// Conv GEMM via split-bf16 MFMA: tu[N][256] = x @ [Wroot|Wrel] (+bias cols<128)
// ---------------------------------------------------------------------------
__global__ __launch_bounds__(256) void conv_mfma(
    const unsigned short* __restrict__ x2,   // [N][256] bf16
    const unsigned short* __restrict__ bimg, // layer image [4][24576]
    float* __restrict__ tu,                  // [N][256] f32
    const float* __restrict__ bias)          // [128]
{
    __shared__ unsigned short Bt[24576];     // 48 KB
    const int tid = threadIdx.x;
    const int cb = blockIdx.x;               // 0..3
    const int rBase = blockIdx.y * 128;

    {   // linear 48KB stage (image pre-swizzled)
        const unsigned short* src = bimg + cb * 24576;
#pragma unroll
        for (int i = 0; i < 12; ++i) {
            const int e = (tid + i * 256) * 8;
            *(uint4*)&Bt[e] = *(const uint4*)&src[e];
        }
    }
    __syncthreads();

    const int lane = tid & 63;
    const int w = tid >> 6;
    const int r0w = rBase + w * 32;
    const int l15 = lane & 15;
    const int kg = lane >> 4;

    f32x4 acc[2][4];
#pragma unroll
    for (int rf = 0; rf < 2; ++rf)
#pragma unroll
        for (int cf = 0; cf < 4; ++cf) acc[rf][cf] = (f32x4){0.f, 0.f, 0.f, 0.f};

    const int rr0 = r0w + l15;
    const int rr1 = r0w + 16 + l15;
    const unsigned short* arow0 = x2 + (size_t)(rr0 < NN ? rr0 : NN - 1) * 256 + kg * 8;
    const unsigned short* arow1 = x2 + (size_t)(rr1 < NN ? rr1 : NN - 1) * 256 + kg * 8;

#pragma unroll
    for (int s = 0; s < 12; ++s) {
        const int acol = (s < 8 ? s : s - 8) * 32;   // [ah|al] then ah again
        const short8 a0 = *(const short8*)(arow0 + acol);
        const short8 a1 = *(const short8*)(arow1 + acol);
        short8 bfr[4];
#pragma unroll
        for (int cf = 0; cf < 4; ++cf) {
            const int c = cf * 16 + l15;
            const int e = (c * 384 + s * 32 + kg * 8) ^ ((c & 7) << 3);
            bfr[cf] = *(const short8*)&Bt[e];
        }
#pragma unroll
        for (int cf = 0; cf < 4; ++cf) {
            acc[0][cf] = __builtin_amdgcn_mfma_f32_16x16x32_bf16(a0, bfr[cf], acc[0][cf], 0, 0, 0);
            acc[1][cf] = __builtin_amdgcn_mfma_f32_16x16x32_bf16(a1, bfr[cf], acc[1][cf], 0, 0, 0);
        }
    }
    // epilogue: D col = lane&15, row = (lane>>4)*4 + reg
    const int c0 = cb * 64;
#pragma unroll
    for (int rf = 0; rf < 2; ++rf) {
#pragma unroll
        for (int reg = 0; reg < 4; ++reg) {
            const int grow = r0w + rf * 16 + kg * 4 + reg;
            if (grow < NN) {
#pragma unroll
                for (int cf = 0; cf < 4; ++cf) {
                    const int gc = c0 + cf * 16 + l15;
                    float v = acc[rf][cf][reg];
                    if (gc < 128) v += bias[gc];
                    tu[(size_t)grow * 256 + gc] = v;
                }
            }
        }
    }
}

// ---------------------------------------------------------------------------
// Gates GEMM via split-bf16 MFMA: gates[256][1536] = qstar2 @ wt
// K' = 2304 = [ah.bh | al.bh | ah.bl]. Grid (24,2), 4 waves, 128rows x 64cols.
// A from qh2 global (fragment-coalesced); B fragments from wt2 image
// (256B-contiguous per (kg,cf) group, L2-resident: 4.7 MB reused all steps).
// ---------------------------------------------------------------------------
__global__ __launch_bounds__(256) void gates_mfma(
    const unsigned short* __restrict__ qh2,  // [256][1536] = [ah(768)|al(768)]
    const unsigned short* __restrict__ wt2,  // [2][96][1536][8]
    float* __restrict__ gates)               // [256][1536]
{
    const int tid = threadIdx.x;
    const int lane = tid & 63;
    const int w = tid >> 6;
    const int c0 = blockIdx.x * 64;
    const int r0w = blockIdx.y * 128 + w * 32;
    const int l15 = lane & 15;
    const int kg = lane >> 4;

    f32x4 acc[2][4];
#pragma unroll
    for (int rf = 0; rf < 2; ++rf)
#pragma unroll
        for (int cf = 0; cf < 4; ++cf) acc[rf][cf] = (f32x4){0.f, 0.f, 0.f, 0.f};

    const unsigned short* arow0 = qh2 + (size_t)(r0w + l15) * 1536 + kg * 8;
    const unsigned short* arow1 = arow0 + 16 * 1536;

#pragma unroll
    for (int p = 0; p < 3; ++p) {
        const int abase = (p == 1) ? 768 : 0;
        const unsigned short* bbase = wt2 + (p == 2 ? 1179648 : 0)
                                    + (size_t)(kg * 1536 + c0 + l15) * 8;
#pragma unroll 4
        for (int km = 0; km < 24; ++km) {
            const short8 a0 = *(const short8*)(arow0 + abase + km * 32);
            const short8 a1 = *(const short8*)(arow1 + abase + km * 32);
#pragma unroll
            for (int cf = 0; cf < 4; ++cf) {
                const short8 bf = *(const short8*)(bbase + (size_t)km * 4 * 1536 * 8 + cf * 128);
                acc[0][cf] = __builtin_amdgcn_mfma_f32_16x16x32_bf16(a0, bf, acc[0][cf], 0, 0, 0);
                acc[1][cf] = __builtin_amdgcn_mfma_f32_16x16x32_bf16(a1, bf, acc[1][cf], 0, 0, 0);
            }
        }
    }
#pragma unroll
    for (int rf = 0; rf < 2; ++rf)
#pragma unroll
        for (int reg = 0; reg < 4; ++reg) {
            const int grow = r0w + rf * 16 + kg * 4 + reg;
#pragma unroll
            for (int cf = 0; cf < 4; ++cf)
                gates[(size_t)grow * 1536 + c0 + cf * 16 + l15] = acc[rf][cf][reg];
        }
}

// ---------------------------------------------------------------------------
// CSR build
// ---------------------------------------------------------------------------
__global__ __launch_bounds__(256) void deg_hist(const int* __restrict__ ei,
                                                int* __restrict__ deg)
{
    const int e = blockIdx.x * 256 + threadIdx.x;
    if (e < EE) atomicAdd(&deg[ei[EE + e]], 1);
}

__global__ __launch_bounds__(256) void scan1(const int* __restrict__ deg,
                                             int* __restrict__ tmp_ex,
                                             int* __restrict__ bsum)
{
    __shared__ int s[256];
    const int i = blockIdx.x * 256 + threadIdx.x;
    const int v = (i < NN) ? deg[i] : 0;
    s[threadIdx.x] = v;
    __syncthreads();
#pragma unroll
    for (int off = 1; off < 256; off <<= 1) {
        const int t = (threadIdx.x >= off) ? s[threadIdx.x - off] : 0;
        __syncthreads();
        s[threadIdx.x] += t;
        __syncthreads();
    }
    tmp_ex[i] = s[threadIdx.x] - v;
    if (threadIdx.x == 255) bsum[blockIdx.x] = s[255];
}

__global__ __launch_bounds__(256) void scan2(const int* __restrict__ bsum,
                                             int* __restrict__ boff)
{
    __shared__ int s[256];
    const int v = (threadIdx.x < 196) ? bsum[threadIdx.x] : 0;
    s[threadIdx.x] = v;
    __syncthreads();
#pragma unroll
    for (int off = 1; off < 256; off <<= 1) {
        const int t = (threadIdx.x >= off) ? s[threadIdx.x - off] : 0;
        __syncthreads();
        s[threadIdx.x] += t;
        __syncthreads();
    }
    if (threadIdx.x < 196) boff[threadIdx.x] = s[threadIdx.x] - v;
}

__global__ __launch_bounds__(256) void scan3(const int* __restrict__ tmp_ex,
                                             const int* __restrict__ boff,
                                             int* __restrict__ rowptr,
                                             int* __restrict__ cursor)
{
    const int i = blockIdx.x * 256 + threadIdx.x;
    if (i < NN) {
        const int r = tmp_ex[i] + boff[blockIdx.x];
        rowptr[i] = r;
        cursor[i] = r;
    }
    if (i == 0) rowptr[NN] = EE;
}

__global__ __launch_bounds__(256) void scatter_edges(const int* __restrict__ ei,
                                                     int* __restrict__ cursor,
                                                     int* __restrict__ col)
{
    const int e = blockIdx.x * 256 + threadIdx.x;
    if (e >= EE) return;
    const int slot = atomicAdd(&cursor[ei[EE + e]], 1);
    col[slot] = ei[e];
}

// ---------------------------------------------------------------------------
// Fused aggregation: xc[n, coloff:+128] = relu(t[n] + sum u[src]); also emits
// split-bf16 copy into x2 (next conv layer's input) when wsplit != 0.
// ---------------------------------------------------------------------------
__global__ __launch_bounds__(256) void agg_relu(const int* __restrict__ rowptr,
                                                const int* __restrict__ col,
                                                const float* __restrict__ tu,
                                                float* __restrict__ xc, int coloff,
                                                unsigned short* __restrict__ x2n,
                                                int wsplit)
{
    const int node = blockIdx.x * 4 + (threadIdx.x >> 6);
    if (node >= NN) return;
    const int lane = threadIdx.x & 63;
    const int b = rowptr[node];
    const int e = rowptr[node + 1];
    const float* u = tu + 128 + lane * 2;

    float2 a0 = *(const float2*)&tu[(size_t)node * 256 + lane * 2];
    float2 a1 = make_float2(0.f, 0.f);
    float2 a2 = make_float2(0.f, 0.f);
    float2 a3 = make_float2(0.f, 0.f);

    int j = b;
    for (; j + 8 <= e; j += 8) {
        const int s0 = col[j + 0], s1 = col[j + 1], s2 = col[j + 2], s3 = col[j + 3];
        const int s4 = col[j + 4], s5 = col[j + 5], s6 = col[j + 6], s7 = col[j + 7];
        const float2 v0 = *(const float2*)(u + (size_t)s0 * 256);
        const float2 v1 = *(const float2*)(u + (size_t)s1 * 256);
        const float2 v2 = *(const float2*)(u + (size_t)s2 * 256);
        const float2 v3 = *(const float2*)(u + (size_t)s3 * 256);
        const float2 v4 = *(const float2*)(u + (size_t)s4 * 256);
        const float2 v5 = *(const float2*)(u + (size_t)s5 * 256);
        const float2 v6 = *(const float2*)(u + (size_t)s6 * 256);
        const float2 v7 = *(const float2*)(u + (size_t)s7 * 256);
        a0.x += v0.x; a0.y += v0.y;  a1.x += v1.x; a1.y += v1.y;
        a2.x += v2.x; a2.y += v2.y;  a3.x += v3.x; a3.y += v3.y;
        a0.x += v4.x; a0.y += v4.y;  a1.x += v5.x; a1.y += v5.y;
        a2.x += v6.x; a2.y += v6.y;  a3.x += v7.x; a3.y += v7.y;
    }
    for (; j < e; j += 4) {
        const bool c1 = (j + 1 < e), c2 = (j + 2 < e), c3 = (j + 3 < e);
        const int s0 = col[j];
        const int s1 = col[c1 ? j + 1 : j];
        const int s2 = col[c2 ? j + 2 : j];
        const int s3 = col[c3 ? j + 3 : j];
        const float2 v0 = *(const float2*)(u + (size_t)s0 * 256);
        const float2 v1 = *(const float2*)(u + (size_t)s1 * 256);
        const float2 v2 = *(const float2*)(u + (size_t)s2 * 256);
        const float2 v3 = *(const float2*)(u + (size_t)s3 * 256);
        a0.x += v0.x;              a0.y += v0.y;
        a1.x += c1 ? v1.x : 0.f;   a1.y += c1 ? v1.y : 0.f;
        a2.x += c2 ? v2.x : 0.f;   a2.y += c2 ? v2.y : 0.f;
        a3.x += c3 ? v3.x : 0.f;   a3.y += c3 ? v3.y : 0.f;
    }
    float2 acc;
    acc.x = (a0.x + a1.x) + (a2.x + a3.x);
    acc.y = (a0.y + a1.y) + (a2.y + a3.y);
    acc.x = fmaxf(acc.x, 0.f);
    acc.y = fmaxf(acc.y, 0.f);
    *(float2*)&xc[(size_t)node * 384 + coloff + lane * 2] = acc;

    if (wsplit) {
        const unsigned short h0 = bf16_rne(acc.x);
        const unsigned short h1 = bf16_rne(acc.y);
        const unsigned short l0 = bf16_rne(acc.x - bf16_tof(h0));
        const unsigned short l1 = bf16_rne(acc.y - bf16_tof(h1));
        unsigned short* p = x2n + (size_t)node * 256 + lane * 2;
        *(unsigned int*)p = (unsigned int)h0 | ((unsigned int)h1 << 16);
        *(unsigned int*)(p + 128) = (unsigned int)l0 | ((unsigned int)l1 << 16);
    }
}

// ---------------------------------------------------------------------------
// Fused LSTM + per-graph attention, ONLINE softmax single pass over xc.
// gates: [256][1536]. qh: [256][768] f32 = [h|r]. qh2: split-bf16 q_star.
// 1024 threads (16 waves) for latency hiding on the xc stream.
// ---------------------------------------------------------------------------
__global__ __launch_bounds__(1024) void lstm_attn(const float* __restrict__ gates,
                                                  const float* __restrict__ b_ih,
                                                  const float* __restrict__ b_hh,
                                                  float* __restrict__ cbuf,
                                                  float* __restrict__ qh,
                                                  unsigned short* __restrict__ qh2,
                                                  const float* __restrict__ xc)
{
    const int b = blockIdx.x;
    const int start = (b * NN + BBg - 1) / BBg;
    const int end = ((b + 1) * NN + BBg - 1) / BBg;
    const int cnt = end - start;  // 195 or 196

    __shared__ float qs[384];
    __shared__ float wm[16], wz[16];
    __shared__ float rp[16][384];

    const int tid = threadIdx.x;
    const int lane = tid & 63;
    const int w = tid >> 6;  // 0..15

    // --- LSTM elementwise for graph b (gate order i,f,g,o) ---
    if (tid < 384) {
        const int d = tid;
        const float* g0 = gates + (size_t)b * 1536;
        float gi = g0[d]        + b_ih[d]        + b_hh[d];
        float gf = g0[384 + d]  + b_ih[384 + d]  + b_hh[384 + d];
        float gg = g0[768 + d]  + b_ih[768 + d]  + b_hh[768 + d];
        float go = g0[1152 + d] + b_ih[1152 + d] + b_hh[1152 + d];
        gi = 1.f / (1.f + expf(-gi));
        gf = 1.f / (1.f + expf(-gf));
        go = 1.f / (1.f + expf(-go));
        const float cc = gf * cbuf[b * 384 + d] + gi * tanhf(gg);
        cbuf[b * 384 + d] = cc;
        const float h = go * tanhf(cc);
        qh[(size_t)b * 768 + d] = h;
        qs[d] = h;
        const unsigned short hi = bf16_rne(h);
        qh2[(size_t)b * 1536 + d] = hi;
        qh2[(size_t)b * 1536 + 768 + d] = bf16_rne(h - bf16_tof(hi));
    }
    __syncthreads();

    float q[6];
#pragma unroll
    for (int j = 0; j < 6; ++j) q[j] = qs[lane + 64 * j];

    // --- online pass: e, running max/sum, r accumulation (all lane-local) ---
    float m = -3.4e38f, Z = 0.f;
    float r[6] = {0.f, 0.f, 0.f, 0.f, 0.f, 0.f};
    for (int i = w; i < cnt; i += 16) {
        const float* xr = xc + (size_t)(start + i) * 384;
        float xv[6], d = 0.f;
#pragma unroll
        for (int j = 0; j < 6; ++j) { xv[j] = xr[lane + 64 * j]; d = fmaf(xv[j], q[j], d); }
#pragma unroll
        for (int s = 32; s > 0; s >>= 1) d += __shfl_xor(d, s);
        const float mn = fmaxf(m, d);
        const float cs = __expf(m - mn);   // 1 when max unchanged
        const float p  = __expf(d - mn);
        Z = Z * cs + p;
#pragma unroll
        for (int j = 0; j < 6; ++j) r[j] = fmaf(r[j], cs, p * xv[j]);
        m = mn;
    }
#pragma unroll
    for (int j = 0; j < 6; ++j) rp[w][lane + 64 * j] = r[j];
    if (lane == 0) { wm[w] = m; wz[w] = Z; }
    __syncthreads();

    // --- combine 16 wave-partials ---
    float M = wm[0];
#pragma unroll
    for (int i = 1; i < 16; ++i) M = fmaxf(M, wm[i]);
    float sc[16];
    float Zt = 0.f;
#pragma unroll
    for (int i = 0; i < 16; ++i) { sc[i] = __expf(wm[i] - M); Zt += wz[i] * sc[i]; }
    const float invZ = 1.f / Zt;
    for (int t = tid; t < 384; t += 1024) {
        float rr = 0.f;
#pragma unroll
        for (int i2 = 0; i2 < 16; ++i2) rr = fmaf(rp[i2][t], sc[i2], rr);
        const float val = rr * invZ;
        qh[(size_t)b * 768 + 384 + t] = val;
        const unsigned short hi = bf16_rne(val);
        qh2[(size_t)b * 1536 + 384 + t] = hi;
        qh2[(size_t)b * 1536 + 1152 + t] = bf16_rne(val - bf16_tof(hi));
    }
}

// h1 = relu(q_star @ lin1_W + b)
__global__ __launch_bounds__(128) void head1(const float* __restrict__ qh,
                                             const float* __restrict__ W,
                                             const float* __restrict__ bias,
                                             float* __restrict__ h1)
{
    const int b = blockIdx.x;
    const int tid = threadIdx.x;
    __shared__ float qs[768];
    for (int k = tid; k < 768; k += 128) qs[k] = qh[(size_t)b * 768 + k];
    __syncthreads();
    float acc = bias[tid];
    for (int k = 0; k < 768; ++k) acc = fmaf(qs[k], W[k * 128 + tid], acc);
    h1[b * 128 + tid] = fmaxf(acc, 0.f);
}

__global__ __launch_bounds__(64) void head2(const float* __restrict__ h1,
                                            const float* __restrict__ W2,
                                            const float* __restrict__ b2,
                                            const float* __restrict__ W3,
                                            const float* __restrict__ b3,
                                            float* __restrict__ out)
{
    const int b = blockIdx.x;
    const int tid = threadIdx.x;
    __shared__ float hs[128];
    __shared__ float h2s[64];
    __shared__ float lg[10];
    for (int k = tid; k < 128; k += 64) hs[k] = h1[b * 128 + k];
    __syncthreads();
    float acc = b2[tid];
    for (int k = 0; k < 128; ++k) acc = fmaf(hs[k], W2[k * 64 + tid], acc);
    h2s[tid] = fmaxf(acc, 0.f);
    __syncthreads();
    if (tid < 10) {
        float a = b3[tid];
        for (int k = 0; k < 64; ++k) a = fmaf(h2s[k], W3[k * 10 + tid], a);
        lg[tid] = a;
    }
    __syncthreads();
    if (tid < 10) {
        float m = lg[0];
        for (int j = 1; j < 10; ++j) m = fmaxf(m, lg[j]);
        float s = 0.f;
        for (int j = 0; j < 10; ++j) s += expf(lg[j] - m);
        out[b * 10 + tid] = lg[tid] - m - logf(s);
    }
}

// ---------------------------------------------------------------------------
extern "C" void kernel_launch(void* const* d_in, const int* in_sizes, int n_in,
                              void* d_out, int out_size, void* d_ws, size_t ws_size,
                              hipStream_t stream)
{
    const float* x     = (const float*)d_in[0];
    const int*   ei    = (const int*)d_in[1];
    const float* W1r   = (const float*)d_in[3];
    const float* W1l   = (const float*)d_in[4];
    const float* b1    = (const float*)d_in[5];
    const float* W2r   = (const float*)d_in[6];
    const float* W2l   = (const float*)d_in[7];
    const float* b2    = (const float*)d_in[8];
    const float* W3r   = (const float*)d_in[9];
    const float* W3l   = (const float*)d_in[10];
    const float* b3    = (const float*)d_in[11];
    const float* W_ih  = (const float*)d_in[12];
    const float* W_hh  = (const float*)d_in[13];
    const float* b_ih  = (const float*)d_in[14];
    const float* b_hh  = (const float*)d_in[15];
    const float* lin1W = (const float*)d_in[16];
    const float* lin1b = (const float*)d_in[17];
    const float* lin2W = (const float*)d_in[18];
    const float* lin2b = (const float*)d_in[19];
    const float* lin3W = (const float*)d_in[20];
    const float* lin3b = (const float*)d_in[21];

    float* ws = (float*)d_ws;
    // workspace layout (float offsets)
    float* xc    = ws;                        // [N][384]           19,200,000
    float* tu    = ws + 19200000;             // [N][256] f32       12,800,000
    // --- set2set region ALIASES tu (tu dead after 3rd agg) ---
    float* qh    = tu;                        // [256][768]            196,608
    float* cbuf  = tu + 196608;               // [256][384]             98,304
    float* gates = tu + 294912;               // [256][1536]           393,216
    unsigned short* qh2 = (unsigned short*)(tu + 688128);  // 393,216 u16
    float* h1    = tu + 884736;               // [256][128]             32,768
    // --- persistent baked images ---
    unsigned short* wt2  = (unsigned short*)(ws + 32000000);  // 2,359,296 u16
    unsigned short* bimg = (unsigned short*)(ws + 33179648);  //   294,912 u16
    unsigned short* x2   = (unsigned short*)(ws + 33327104);  // 12,800,000 u16
    int*   ib    = (int*)(ws + 39727104);
    int* deg     = ib;                        // 50,000 (zeroed)
    int* rowptr  = ib + 50000;                // 50,001
    int* cursor  = ib + 100001;               // 50,000
    int* tmp_ex  = ib + 150001;               // 50,176
    int* bsum    = ib + 200177;               // 256
    int* boff    = ib + 200433;               // 256
    int* col     = ib + 200689;               // 600,000
    float* out   = (float*)d_out;

    hipMemsetAsync(deg, 0, 50000 * sizeof(int), stream);

    // weight prep
    bake_wt2<<<9216, 256, 0, stream>>>(W_ih, W_hh, wt2);
    bake_bimg<<<1152, 256, 0, stream>>>(W1r, W1l, W2r, W2l, W3r, W3l, bimg);
    prep_x2<<<25000, 256, 0, stream>>>(x, x2);

    // CSR build
    deg_hist<<<2344, 256, 0, stream>>>(ei, deg);
    scan1<<<196, 256, 0, stream>>>(deg, tmp_ex, bsum);
    scan2<<<1, 256, 0, stream>>>(bsum, boff);
    scan3<<<196, 256, 0, stream>>>(tmp_ex, boff, rowptr, cursor);
    scatter_edges<<<2344, 256, 0, stream>>>(ei, cursor, col);

    // 3 GraphConv layers: MFMA GEMM -> gather+relu (+ split emit for next)
    const float* biases[3] = {b1, b2, b3};
    for (int l = 0; l < 3; ++l) {
        conv_mfma<<<dim3(4, 391), 256, 0, stream>>>(
            x2, bimg + l * 4 * 24576, tu, biases[l]);
        agg_relu<<<12500, 256, 0, stream>>>(rowptr, col, tu, xc, l * 128,
                                            x2, (l < 2) ? 1 : 0);
    }

    // zero LSTM state (qh + cbuf contiguous) and split q_star (AFTER conv:
    // these alias tu, which is dead once the 3rd agg_relu has run)
    hipMemsetAsync(qh, 0, (196608 + 98304) * sizeof(float), stream);
    hipMemsetAsync(qh2, 0, 393216 * sizeof(unsigned short), stream);

    // Set2Set: 10 steps (MFMA gates GEMM -> fused LSTM+attention)
    for (int s = 0; s < 10; ++s) {
        gates_mfma<<<dim3(24, 2), 256, 0, stream>>>(qh2, wt2, gates);
        lstm_attn<<<256, 1024, 0, stream>>>(gates, b_ih, b_hh, cbuf, qh, qh2, xc);
    }

    // MLP head
    head1<<<256, 128, 0, stream>>>(qh, lin1W, lin1b, h1);
    head2<<<256, 64, 0, stream>>>(h1, lin2W, lin2b, lin3W, lin3b, out);
}

// Round 7
// 779.809 us; speedup vs baseline: 1.3022x; 1.3022x over previous
//
#include <hip/hip_runtime.h>
#include <hip/hip_bf16.h>
#include <cstddef>

// Problem constants (match reference)
constexpr int NN = 50000;   // nodes
constexpr int EE = 600000;  // edges
constexpr int BBg = 256;    // graphs

typedef __attribute__((ext_vector_type(8))) short short8;
typedef __attribute__((ext_vector_type(4))) float f32x4;

// bf16 round-to-nearest-even split helpers
__device__ __forceinline__ unsigned short bf16_rne(float f) {
    unsigned int u = __float_as_uint(f);
    unsigned int r = u + 0x7fffu + ((u >> 16) & 1u);
    return (unsigned short)(r >> 16);
}
__device__ __forceinline__ float bf16_tof(unsigned short h) {
    return __uint_as_float(((unsigned int)h) << 16);
}

// ---------------------------------------------------------------------------
// Split conv weights into pre-swizzled per-cblock LDS images.
// Image: [l][cb][64 cols][384 k'] bf16, elem ^= ((c&7)<<3).
// ---------------------------------------------------------------------------
__global__ __launch_bounds__(256) void bake_bimg(
    const float* __restrict__ Wr1, const float* __restrict__ Wl1,
    const float* __restrict__ Wr2, const float* __restrict__ Wl2,
    const float* __restrict__ Wr3, const float* __restrict__ Wl3,
    unsigned short* __restrict__ bimg)
{
    int t = blockIdx.x * 256 + threadIdx.x;      // 3*4*64*384 = 294912
    const int kp = t % 384;
    int rest = t / 384;
    const int c = rest & 63;  rest >>= 6;
    const int cb = rest & 3;  rest >>= 2;
    const int l = rest;                           // 0..2
    const int kk = kp & 127;
    const int gc = cb * 64 + c;
    const float* W;
    if (gc < 128) W = (l == 0) ? Wr1 : (l == 1) ? Wr2 : Wr3;
    else          W = (l == 0) ? Wl1 : (l == 1) ? Wl2 : Wl3;
    const float v = W[kk * 128 + (gc & 127)];
    const unsigned short hi = bf16_rne(v);
    unsigned short out = hi;
    if (kp >= 256) out = bf16_rne(v - bf16_tof(hi));
    const int e = (c * 384 + kp) ^ ((c & 7) << 3);
    bimg[(l * 4 + cb) * 24576 + e] = out;
}

// x (f32 [N][128]) -> x2 (bf16 [N][256] = [ah|al])
__global__ __launch_bounds__(256) void prep_x2(const float* __restrict__ x,
                                               unsigned short* __restrict__ x2)
{
    const int t = blockIdx.x * 256 + threadIdx.x;
    if (t >= NN * 128) return;
    const int n = t >> 7, k = t & 127;
    const float v = x[t];
    const unsigned short hi = bf16_rne(v);
    x2[(size_t)n * 256 + k] = hi;
    x2[(size_t)n * 256 + 128 + k] = bf16_rne(v - bf16_tof(hi));
}

// ---------------------------------------------------------------------------
// Combined LSTM weight wt[k][j] = W_ih[j][k] (+W_hh[j][k] for k<384), split
// hi/lo bf16, fragment-layout image: wt2[v][k'/8][1536 cols][8].
// ---------------------------------------------------------------------------
__global__ __launch_bounds__(256) void bake_wt2(const float* __restrict__ w_ih,
                                                const float* __restrict__ w_hh,
                                                unsigned short* __restrict__ wt2)
{
    const int t = blockIdx.x * 256 + threadIdx.x;  // 2*96*1536*8 = 2,359,296
    const int o = t & 7;
    const int j = (t >> 3) % 1536;
    const int rest = (t >> 3) / 1536;  // 0..191
    const int kg = rest % 96;
    const int v = rest / 96;           // 0=hi, 1=lo
    const int k = kg * 8 + o;          // 0..767
    float val = w_ih[(size_t)j * 768 + k];
    if (k < 384) val += w_hh[(size_t)j * 384 + k];
    const unsigned short hi = bf16_rne(val);
    wt2[t] = v ? bf16_rne(val - bf16_tof(hi)) : hi;
}

// ---------------------------------------------------------------------------
// Conv GEMM via split-bf16 MFMA: tu[N][256] = x @ [Wroot|Wrel] (+bias cols<128)
// ---------------------------------------------------------------------------
__global__ __launch_bounds__(256) void conv_mfma(
    const unsigned short* __restrict__ x2,   // [N][256] bf16
    const unsigned short* __restrict__ bimg, // layer image [4][24576]
    float* __restrict__ tu,                  // [N][256] f32
    const float* __restrict__ bias)          // [128]
{
    __shared__ unsigned short Bt[24576];     // 48 KB
    const int tid = threadIdx.x;
    const int cb = blockIdx.x;               // 0..3
    const int rBase = blockIdx.y * 128;

    {   // linear 48KB stage (image pre-swizzled)
        const unsigned short* src = bimg + cb * 24576;
#pragma unroll
        for (int i = 0; i < 12; ++i) {
            const int e = (tid + i * 256) * 8;
            *(uint4*)&Bt[e] = *(const uint4*)&src[e];
        }
    }
    __syncthreads();

    const int lane = tid & 63;
    const int w = tid >> 6;
    const int r0w = rBase + w * 32;
    const int l15 = lane & 15;
    const int kg = lane >> 4;

    f32x4 acc[2][4];
#pragma unroll
    for (int rf = 0; rf < 2; ++rf)
#pragma unroll
        for (int cf = 0; cf < 4; ++cf) acc[rf][cf] = (f32x4){0.f, 0.f, 0.f, 0.f};

    const int rr0 = r0w + l15;
    const int rr1 = r0w + 16 + l15;
    const unsigned short* arow0 = x2 + (size_t)(rr0 < NN ? rr0 : NN - 1) * 256 + kg * 8;
    const unsigned short* arow1 = x2 + (size_t)(rr1 < NN ? rr1 : NN - 1) * 256 + kg * 8;

#pragma unroll
    for (int s = 0; s < 12; ++s) {
        const int acol = (s < 8 ? s : s - 8) * 32;   // [ah|al] then ah again
        const short8 a0 = *(const short8*)(arow0 + acol);
        const short8 a1 = *(const short8*)(arow1 + acol);
        short8 bfr[4];
#pragma unroll
        for (int cf = 0; cf < 4; ++cf) {
            const int c = cf * 16 + l15;
            const int e = (c * 384 + s * 32 + kg * 8) ^ ((c & 7) << 3);
            bfr[cf] = *(const short8*)&Bt[e];
        }
#pragma unroll
        for (int cf = 0; cf < 4; ++cf) {
            acc[0][cf] = __builtin_amdgcn_mfma_f32_16x16x32_bf16(a0, bfr[cf], acc[0][cf], 0, 0, 0);
            acc[1][cf] = __builtin_amdgcn_mfma_f32_16x16x32_bf16(a1, bfr[cf], acc[1][cf], 0, 0, 0);
        }
    }
    // epilogue: D col = lane&15, row = (lane>>4)*4 + reg
    const int c0 = cb * 64;
#pragma unroll
    for (int rf = 0; rf < 2; ++rf) {
#pragma unroll
        for (int reg = 0; reg < 4; ++reg) {
            const int grow = r0w + rf * 16 + kg * 4 + reg;
            if (grow < NN) {
#pragma unroll
                for (int cf = 0; cf < 4; ++cf) {
                    const int gc = c0 + cf * 16 + l15;
                    float v = acc[rf][cf][reg];
                    if (gc < 128) v += bias[gc];
                    tu[(size_t)grow * 256 + gc] = v;
                }
            }
        }
    }
}

// ---------------------------------------------------------------------------
// Gates GEMM via split-bf16 MFMA, SPLIT-K over the 3 products (blockIdx.z=p):
// gpart[p][256][1536] partials; p0 = ah.bh, p1 = al.bh, p2 = ah.bl.
// Grid (24,2,3) = 144 blocks -> 1/3 the serial K-chain per block.
// ---------------------------------------------------------------------------
__global__ __launch_bounds__(256) void gates_mfma(
    const unsigned short* __restrict__ qh2,  // [256][1536] = [ah(768)|al(768)]
    const unsigned short* __restrict__ wt2,  // [2][96][1536][8]
    float* __restrict__ gpart)               // [3][256][1536]
{
    const int tid = threadIdx.x;
    const int lane = tid & 63;
    const int w = tid >> 6;
    const int c0 = blockIdx.x * 64;
    const int r0w = blockIdx.y * 128 + w * 32;
    const int p = blockIdx.z;                // 0..2
    const int l15 = lane & 15;
    const int kg = lane >> 4;

    f32x4 acc[2][4];
#pragma unroll
    for (int rf = 0; rf < 2; ++rf)
#pragma unroll
        for (int cf = 0; cf < 4; ++cf) acc[rf][cf] = (f32x4){0.f, 0.f, 0.f, 0.f};

    const int abase = (p == 1) ? 768 : 0;
    const unsigned short* arow0 = qh2 + (size_t)(r0w + l15) * 1536 + abase + kg * 8;
    const unsigned short* arow1 = arow0 + 16 * 1536;
    const unsigned short* bbase = wt2 + (p == 2 ? 1179648 : 0)
                                + (size_t)(kg * 1536 + c0 + l15) * 8;

#pragma unroll 4
    for (int km = 0; km < 24; ++km) {
        const short8 a0 = *(const short8*)(arow0 + km * 32);
        const short8 a1 = *(const short8*)(arow1 + km * 32);
#pragma unroll
        for (int cf = 0; cf < 4; ++cf) {
            const short8 bf = *(const short8*)(bbase + (size_t)km * 4 * 1536 * 8 + cf * 128);
            acc[0][cf] = __builtin_amdgcn_mfma_f32_16x16x32_bf16(a0, bf, acc[0][cf], 0, 0, 0);
            acc[1][cf] = __builtin_amdgcn_mfma_f32_16x16x32_bf16(a1, bf, acc[1][cf], 0, 0, 0);
        }
    }
    float* gout = gpart + (size_t)p * 393216;
#pragma unroll
    for (int rf = 0; rf < 2; ++rf)
#pragma unroll
        for (int reg = 0; reg < 4; ++reg) {
            const int grow = r0w + rf * 16 + kg * 4 + reg;
#pragma unroll
            for (int cf = 0; cf < 4; ++cf)
                gout[(size_t)grow * 1536 + c0 + cf * 16 + l15] = acc[rf][cf][reg];
        }
}

// ---------------------------------------------------------------------------
// CSR build
// ---------------------------------------------------------------------------
__global__ __launch_bounds__(256) void deg_hist(const int* __restrict__ ei,
                                                int* __restrict__ deg)
{
    const int e = blockIdx.x * 256 + threadIdx.x;
    if (e < EE) atomicAdd(&deg[ei[EE + e]], 1);
}

__global__ __launch_bounds__(256) void scan1(const int* __restrict__ deg,
                                             int* __restrict__ tmp_ex,
                                             int* __restrict__ bsum)
{
    __shared__ int s[256];
    const int i = blockIdx.x * 256 + threadIdx.x;
    const int v = (i < NN) ? deg[i] : 0;
    s[threadIdx.x] = v;
    __syncthreads();
#pragma unroll
    for (int off = 1; off < 256; off <<= 1) {
        const int t = (threadIdx.x >= off) ? s[threadIdx.x - off] : 0;
        __syncthreads();
        s[threadIdx.x] += t;
        __syncthreads();
    }
    tmp_ex[i] = s[threadIdx.x] - v;
    if (threadIdx.x == 255) bsum[blockIdx.x] = s[255];
}

__global__ __launch_bounds__(256) void scan2(const int* __restrict__ bsum,
                                             int* __restrict__ boff)
{
    __shared__ int s[256];
    const int v = (threadIdx.x < 196) ? bsum[threadIdx.x] : 0;
    s[threadIdx.x] = v;
    __syncthreads();
#pragma unroll
    for (int off = 1; off < 256; off <<= 1) {
        const int t = (threadIdx.x >= off) ? s[threadIdx.x - off] : 0;
        __syncthreads();
        s[threadIdx.x] += t;
        __syncthreads();
    }
    if (threadIdx.x < 196) boff[threadIdx.x] = s[threadIdx.x] - v;
}

__global__ __launch_bounds__(256) void scan3(const int* __restrict__ tmp_ex,
                                             const int* __restrict__ boff,
                                             int* __restrict__ rowptr,
                                             int* __restrict__ cursor)
{
    const int i = blockIdx.x * 256 + threadIdx.x;
    if (i < NN) {
        const int r = tmp_ex[i] + boff[blockIdx.x];
        rowptr[i] = r;
        cursor[i] = r;
    }
    if (i == 0) rowptr[NN] = EE;
}

__global__ __launch_bounds__(256) void scatter_edges(const int* __restrict__ ei,
                                                     int* __restrict__ cursor,
                                                     int* __restrict__ col)
{
    const int e = blockIdx.x * 256 + threadIdx.x;
    if (e >= EE) return;
    const int slot = atomicAdd(&cursor[ei[EE + e]], 1);
    col[slot] = ei[e];
}

// ---------------------------------------------------------------------------
// Fused aggregation: xc[n, coloff:+128] = relu(t[n] + sum u[src]); also emits
// split-bf16 copy into x2 (next conv layer's input) when wsplit != 0.
// ---------------------------------------------------------------------------
__global__ __launch_bounds__(256) void agg_relu(const int* __restrict__ rowptr,
                                                const int* __restrict__ col,
                                                const float* __restrict__ tu,
                                                float* __restrict__ xc, int coloff,
                                                unsigned short* __restrict__ x2n,
                                                int wsplit)
{
    const int node = blockIdx.x * 4 + (threadIdx.x >> 6);
    if (node >= NN) return;
    const int lane = threadIdx.x & 63;
    const int b = rowptr[node];
    const int e = rowptr[node + 1];
    const float* u = tu + 128 + lane * 2;

    float2 a0 = *(const float2*)&tu[(size_t)node * 256 + lane * 2];
    float2 a1 = make_float2(0.f, 0.f);
    float2 a2 = make_float2(0.f, 0.f);
    float2 a3 = make_float2(0.f, 0.f);

    int j = b;
    for (; j + 8 <= e; j += 8) {
        const int s0 = col[j + 0], s1 = col[j + 1], s2 = col[j + 2], s3 = col[j + 3];
        const int s4 = col[j + 4], s5 = col[j + 5], s6 = col[j + 6], s7 = col[j + 7];
        const float2 v0 = *(const float2*)(u + (size_t)s0 * 256);
        const float2 v1 = *(const float2*)(u + (size_t)s1 * 256);
        const float2 v2 = *(const float2*)(u + (size_t)s2 * 256);
        const float2 v3 = *(const float2*)(u + (size_t)s3 * 256);
        const float2 v4 = *(const float2*)(u + (size_t)s4 * 256);
        const float2 v5 = *(const float2*)(u + (size_t)s5 * 256);
        const float2 v6 = *(const float2*)(u + (size_t)s6 * 256);
        const float2 v7 = *(const float2*)(u + (size_t)s7 * 256);
        a0.x += v0.x; a0.y += v0.y;  a1.x += v1.x; a1.y += v1.y;
        a2.x += v2.x; a2.y += v2.y;  a3.x += v3.x; a3.y += v3.y;
        a0.x += v4.x; a0.y += v4.y;  a1.x += v5.x; a1.y += v5.y;
        a2.x += v6.x; a2.y += v6.y;  a3.x += v7.x; a3.y += v7.y;
    }
    for (; j < e; j += 4) {
        const bool c1 = (j + 1 < e), c2 = (j + 2 < e), c3 = (j + 3 < e);
        const int s0 = col[j];
        const int s1 = col[c1 ? j + 1 : j];
        const int s2 = col[c2 ? j + 2 : j];
        const int s3 = col[c3 ? j + 3 : j];
        const float2 v0 = *(const float2*)(u + (size_t)s0 * 256);
        const float2 v1 = *(const float2*)(u + (size_t)s1 * 256);
        const float2 v2 = *(const float2*)(u + (size_t)s2 * 256);
        const float2 v3 = *(const float2*)(u + (size_t)s3 * 256);
        a0.x += v0.x;              a0.y += v0.y;
        a1.x += c1 ? v1.x : 0.f;   a1.y += c1 ? v1.y : 0.f;
        a2.x += c2 ? v2.x : 0.f;   a2.y += c2 ? v2.y : 0.f;
        a3.x += c3 ? v3.x : 0.f;   a3.y += c3 ? v3.y : 0.f;
    }
    float2 acc;
    acc.x = (a0.x + a1.x) + (a2.x + a3.x);
    acc.y = (a0.y + a1.y) + (a2.y + a3.y);
    acc.x = fmaxf(acc.x, 0.f);
    acc.y = fmaxf(acc.y, 0.f);
    *(float2*)&xc[(size_t)node * 384 + coloff + lane * 2] = acc;

    if (wsplit) {
        const unsigned short h0 = bf16_rne(acc.x);
        const unsigned short h1 = bf16_rne(acc.y);
        const unsigned short l0 = bf16_rne(acc.x - bf16_tof(h0));
        const unsigned short l1 = bf16_rne(acc.y - bf16_tof(h1));
        unsigned short* p = x2n + (size_t)node * 256 + lane * 2;
        *(unsigned int*)p = (unsigned int)h0 | ((unsigned int)h1 << 16);
        *(unsigned int*)(p + 128) = (unsigned int)l0 | ((unsigned int)l1 << 16);
    }
}

// ---------------------------------------------------------------------------
// Fused LSTM + per-graph attention, ONLINE softmax with 4-row ILP.
// gpart: [3][256][1536] partial gates. qh: [256][768] f32 = [h|r].
// qh2: split-bf16 q_star. 512 threads, one block per graph.
// ---------------------------------------------------------------------------
__global__ __launch_bounds__(512) void lstm_attn(const float* __restrict__ gpart,
                                                 const float* __restrict__ b_ih,
                                                 const float* __restrict__ b_hh,
                                                 float* __restrict__ cbuf,
                                                 float* __restrict__ qh,
                                                 unsigned short* __restrict__ qh2,
                                                 const float* __restrict__ xc)
{
    const int b = blockIdx.x;
    const int start = (b * NN + BBg - 1) / BBg;
    const int end = ((b + 1) * NN + BBg - 1) / BBg;
    const int cnt = end - start;  // 195 or 196

    __shared__ float qs[384];
    __shared__ float wm[8], wz[8];
    __shared__ float rp[8][384];

    const int tid = threadIdx.x;
    const int lane = tid & 63;
    const int w = tid >> 6;  // 0..7

    // --- LSTM elementwise for graph b (gate order i,f,g,o), 3-partial sum ---
    if (tid < 384) {
        const int d = tid;
        const float* g0 = gpart + (size_t)b * 1536;
        const float* g1 = g0 + 393216;
        const float* g2 = g1 + 393216;
        float gi = g0[d]        + g1[d]        + g2[d]        + b_ih[d]        + b_hh[d];
        float gf = g0[384 + d]  + g1[384 + d]  + g2[384 + d]  + b_ih[384 + d]  + b_hh[384 + d];
        float gg = g0[768 + d]  + g1[768 + d]  + g2[768 + d]  + b_ih[768 + d]  + b_hh[768 + d];
        float go = g0[1152 + d] + g1[1152 + d] + g2[1152 + d] + b_ih[1152 + d] + b_hh[1152 + d];
        gi = 1.f / (1.f + expf(-gi));
        gf = 1.f / (1.f + expf(-gf));
        go = 1.f / (1.f + expf(-go));
        const float cc = gf * cbuf[b * 384 + d] + gi * tanhf(gg);
        cbuf[b * 384 + d] = cc;
        const float h = go * tanhf(cc);
        qh[(size_t)b * 768 + d] = h;
        qs[d] = h;
        const unsigned short hi = bf16_rne(h);
        qh2[(size_t)b * 1536 + d] = hi;
        qh2[(size_t)b * 1536 + 768 + d] = bf16_rne(h - bf16_tof(hi));
    }
    __syncthreads();

    float q[6];
#pragma unroll
    for (int j = 0; j < 6; ++j) q[j] = qs[lane + 64 * j];

    // --- online pass, 4 rows per iteration (24 loads in flight) ---
    float m = -3.4e38f, Z = 0.f;
    float r[6] = {0.f, 0.f, 0.f, 0.f, 0.f, 0.f};
    int i = w;
    for (; i + 24 < cnt; i += 32) {
        const float* xr0 = xc + (size_t)(start + i) * 384 + lane;
        const float* xr1 = xc + (size_t)(start + i + 8) * 384 + lane;
        const float* xr2 = xc + (size_t)(start + i + 16) * 384 + lane;
        const float* xr3 = xc + (size_t)(start + i + 24) * 384 + lane;
        float xv0[6], xv1[6], xv2[6], xv3[6];
#pragma unroll
        for (int j = 0; j < 6; ++j) {
            xv0[j] = xr0[64 * j]; xv1[j] = xr1[64 * j];
            xv2[j] = xr2[64 * j]; xv3[j] = xr3[64 * j];
        }
        float d0 = 0.f, d1 = 0.f, d2 = 0.f, d3 = 0.f;
#pragma unroll
        for (int j = 0; j < 6; ++j) {
            d0 = fmaf(xv0[j], q[j], d0); d1 = fmaf(xv1[j], q[j], d1);
            d2 = fmaf(xv2[j], q[j], d2); d3 = fmaf(xv3[j], q[j], d3);
        }
#pragma unroll
        for (int s = 32; s > 0; s >>= 1) {
            d0 += __shfl_xor(d0, s); d1 += __shfl_xor(d1, s);
            d2 += __shfl_xor(d2, s); d3 += __shfl_xor(d3, s);
        }
        // flash-style quad update (exact online recurrence)
        const float mn = fmaxf(fmaxf(fmaxf(m, d0), fmaxf(d1, d2)), d3);
        const float cs = __expf(m - mn);
        const float p0 = __expf(d0 - mn), p1 = __expf(d1 - mn);
        const float p2 = __expf(d2 - mn), p3 = __expf(d3 - mn);
        Z = Z * cs + ((p0 + p1) + (p2 + p3));
#pragma unroll
        for (int j = 0; j < 6; ++j) {
            float t = r[j] * cs;
            t = fmaf(p0, xv0[j], t); t = fmaf(p1, xv1[j], t);
            t = fmaf(p2, xv2[j], t); t = fmaf(p3, xv3[j], t);
            r[j] = t;
        }
        m = mn;
    }
    for (; i < cnt; i += 8) {  // tail, single row
        const float* xr = xc + (size_t)(start + i) * 384 + lane;
        float xv[6], d = 0.f;
#pragma unroll
        for (int j = 0; j < 6; ++j) { xv[j] = xr[64 * j]; d = fmaf(xv[j], q[j], d); }
#pragma unroll
        for (int s = 32; s > 0; s >>= 1) d += __shfl_xor(d, s);
        const float mn = fmaxf(m, d);
        const float cs = __expf(m - mn);
        const float p = __expf(d - mn);
        Z = Z * cs + p;
#pragma unroll
        for (int j = 0; j < 6; ++j) r[j] = fmaf(r[j], cs, p * xv[j]);
        m = mn;
    }
#pragma unroll
    for (int j = 0; j < 6; ++j) rp[w][lane + 64 * j] = r[j];
    if (lane == 0) { wm[w] = m; wz[w] = Z; }
    __syncthreads();

    // --- combine 8 wave-partials ---
    float M = wm[0];
#pragma unroll
    for (int i2 = 1; i2 < 8; ++i2) M = fmaxf(M, wm[i2]);
    float sc[8];
    float Zt = 0.f;
#pragma unroll
    for (int i2 = 0; i2 < 8; ++i2) { sc[i2] = __expf(wm[i2] - M); Zt += wz[i2] * sc[i2]; }
    const float invZ = 1.f / Zt;
    for (int t = tid; t < 384; t += 512) {
        float rr = 0.f;
#pragma unroll
        for (int i2 = 0; i2 < 8; ++i2) rr = fmaf(rp[i2][t], sc[i2], rr);
        const float val = rr * invZ;
        qh[(size_t)b * 768 + 384 + t] = val;
        const unsigned short hi = bf16_rne(val);
        qh2[(size_t)b * 1536 + 384 + t] = hi;
        qh2[(size_t)b * 1536 + 1152 + t] = bf16_rne(val - bf16_tof(hi));
    }
}

// h1 = relu(q_star @ lin1_W + b)
__global__ __launch_bounds__(128) void head1(const float* __restrict__ qh,
                                             const float* __restrict__ W,
                                             const float* __restrict__ bias,
                                             float* __restrict__ h1)
{
    const int b = blockIdx.x;
    const int tid = threadIdx.x;
    __shared__ float qs[768];
    for (int k = tid; k < 768; k += 128) qs[k] = qh[(size_t)b * 768 + k];
    __syncthreads();
    float acc = bias[tid];
    for (int k = 0; k < 768; ++k) acc = fmaf(qs[k], W[k * 128 + tid], acc);
    h1[b * 128 + tid] = fmaxf(acc, 0.f);
}

__global__ __launch_bounds__(64) void head2(const float* __restrict__ h1,
                                            const float* __restrict__ W2,
                                            const float* __restrict__ b2,
                                            const float* __restrict__ W3,
                                            const float* __restrict__ b3,
                                            float* __restrict__ out)
{
    const int b = blockIdx.x;
    const int tid = threadIdx.x;
    __shared__ float hs[128];
    __shared__ float h2s[64];
    __shared__ float lg[10];
    for (int k = tid; k < 128; k += 64) hs[k] = h1[b * 128 + k];
    __syncthreads();
    float acc = b2[tid];
    for (int k = 0; k < 128; ++k) acc = fmaf(hs[k], W2[k * 64 + tid], acc);
    h2s[tid] = fmaxf(acc, 0.f);
    __syncthreads();
    if (tid < 10) {
        float a = b3[tid];
        for (int k = 0; k < 64; ++k) a = fmaf(h2s[k], W3[k * 10 + tid], a);
        lg[tid] = a;
    }
    __syncthreads();
    if (tid < 10) {
        float m = lg[0];
        for (int j = 1; j < 10; ++j) m = fmaxf(m, lg[j]);
        float s = 0.f;
        for (int j = 0; j < 10; ++j) s += expf(lg[j] - m);
        out[b * 10 + tid] = lg[tid] - m - logf(s);
    }
}

// ---------------------------------------------------------------------------
extern "C" void kernel_launch(void* const* d_in, const int* in_sizes, int n_in,
                              void* d_out, int out_size, void* d_ws, size_t ws_size,
                              hipStream_t stream)
{
    const float* x     = (const float*)d_in[0];
    const int*   ei    = (const int*)d_in[1];
    const float* W1r   = (const float*)d_in[3];
    const float* W1l   = (const float*)d_in[4];
    const float* b1    = (const float*)d_in[5];
    const float* W2r   = (const float*)d_in[6];
    const float* W2l   = (const float*)d_in[7];
    const float* b2    = (const float*)d_in[8];
    const float* W3r   = (const float*)d_in[9];
    const float* W3l   = (const float*)d_in[10];
    const float* b3    = (const float*)d_in[11];
    const float* W_ih  = (const float*)d_in[12];
    const float* W_hh  = (const float*)d_in[13];
    const float* b_ih  = (const float*)d_in[14];
    const float* b_hh  = (const float*)d_in[15];
    const float* lin1W = (const float*)d_in[16];
    const float* lin1b = (const float*)d_in[17];
    const float* lin2W = (const float*)d_in[18];
    const float* lin2b = (const float*)d_in[19];
    const float* lin3W = (const float*)d_in[20];
    const float* lin3b = (const float*)d_in[21];

    float* ws = (float*)d_ws;
    // workspace layout (float offsets)
    float* xc    = ws;                        // [N][384]           19,200,000
    float* tu    = ws + 19200000;             // [N][256] f32       12,800,000
    // --- set2set region ALIASES tu (tu dead after 3rd agg) ---
    float* qh    = tu;                        // [256][768]            196,608
    float* cbuf  = tu + 196608;               // [256][384]             98,304
    float* gpart = tu + 294912;               // [3][256][1536]      1,179,648
    unsigned short* qh2 = (unsigned short*)(tu + 1474560);  // 393,216 u16
    float* h1    = tu + 1671168;              // [256][128]             32,768
    // --- persistent baked images ---
    unsigned short* wt2  = (unsigned short*)(ws + 32000000);  // 2,359,296 u16
    unsigned short* bimg = (unsigned short*)(ws + 33179648);  //   294,912 u16
    unsigned short* x2   = (unsigned short*)(ws + 33327104);  // 12,800,000 u16
    int*   ib    = (int*)(ws + 39727104);
    int* deg     = ib;                        // 50,000 (zeroed)
    int* rowptr  = ib + 50000;                // 50,001
    int* cursor  = ib + 100001;               // 50,000
    int* tmp_ex  = ib + 150001;               // 50,176
    int* bsum    = ib + 200177;               // 256
    int* boff    = ib + 200433;               // 256
    int* col     = ib + 200689;               // 600,000
    float* out   = (float*)d_out;

    hipMemsetAsync(deg, 0, 50000 * sizeof(int), stream);

    // weight prep
    bake_wt2<<<9216, 256, 0, stream>>>(W_ih, W_hh, wt2);
    bake_bimg<<<1152, 256, 0, stream>>>(W1r, W1l, W2r, W2l, W3r, W3l, bimg);
    prep_x2<<<25000, 256, 0, stream>>>(x, x2);

    // CSR build
    deg_hist<<<2344, 256, 0, stream>>>(ei, deg);
    scan1<<<196, 256, 0, stream>>>(deg, tmp_ex, bsum);
    scan2<<<1, 256, 0, stream>>>(bsum, boff);
    scan3<<<196, 256, 0, stream>>>(tmp_ex, boff, rowptr, cursor);
    scatter_edges<<<2344, 256, 0, stream>>>(ei, cursor, col);

    // 3 GraphConv layers: MFMA GEMM -> gather+relu (+ split emit for next)
    const float* biases[3] = {b1, b2, b3};
    for (int l = 0; l < 3; ++l) {
        conv_mfma<<<dim3(4, 391), 256, 0, stream>>>(
            x2, bimg + l * 4 * 24576, tu, biases[l]);
        agg_relu<<<12500, 256, 0, stream>>>(rowptr, col, tu, xc, l * 128,
                                            x2, (l < 2) ? 1 : 0);
    }

    // zero LSTM state (qh + cbuf contiguous) and split q_star (AFTER conv:
    // these alias tu, which is dead once the 3rd agg_relu has run)
    hipMemsetAsync(qh, 0, (196608 + 98304) * sizeof(float), stream);
    hipMemsetAsync(qh2, 0, 393216 * sizeof(unsigned short), stream);

    // Set2Set: 10 steps (split-K MFMA gates GEMM -> fused LSTM+attention)
    for (int s = 0; s < 10; ++s) {
        gates_mfma<<<dim3(24, 2, 3), 256, 0, stream>>>(qh2, wt2, gpart);
        lstm_attn<<<256, 512, 0, stream>>>(gpart, b_ih, b_hh, cbuf, qh, qh2, xc);
    }

    // MLP head
    head1<<<256, 128, 0, stream>>>(qh, lin1W, lin1b, h1);
    head2<<<256, 64, 0, stream>>>(h1, lin2W, lin2b, lin3W, lin3b, out);
}